// Round 2
// baseline (100.636 us; speedup 1.0000x reference)
//
#include <hip/hip_runtime.h>
#include <hip/hip_cooperative_groups.h>

#define BB 384
#define DD 256           // floats per row; 64 float4
#define F4 (DD / 4)      // 64
#define APB 2            // anchors per block
#define NBLK (BB / APB)  // 192 blocks
#define NT 512           // 8 waves/block -> 1536 waves on 1024 SIMDs
#define MARGIN 0.2f

namespace cg = cooperative_groups;

// ---------------------------------------------------------------------------
// Single cooperative kernel: one block (512 threads) per APB=2 anchors.
// Dist phase: 8 waves x 48 rows, 4 rows/iter, unroll 4 => 16 float4 loads in
// flight per wave (HBM-latency hiding after the 256MiB poison fill evicts x
// from L2/L3). lane = 16*rr + dd; one instruction reads float4 f=16k+dd of
// rows b0+rr (4 contiguous 256B segments). Anchor fragments in registers;
// 16-lane shfl_xor butterfly reduces each row's diff^2 partials.
// Triplet phase: block halves process the two anchors CONCURRENTLY
// (tid<256 -> anchor a0, tid>=256 -> anchor a0+1), thresholds precomputed.
// Finalize: grid.sync(), then block 0 reduces the 384 partial pairs — no
// second kernel launch, no GPU-idle single-block tail dispatch.
// ---------------------------------------------------------------------------
__global__ __launch_bounds__(NT) void triplet_coop_kernel(
    const float* __restrict__ x,
    const int* __restrict__ labels,
    double* __restrict__ partial_num,
    double* __restrict__ partial_den,
    float* __restrict__ out) {
    __shared__ int    s_lab[BB];
    __shared__ float  s_d[APB][BB];
    __shared__ float  s_t[APB][BB];   // margin + d[a, p] for each positive
    __shared__ int    s_np[APB], s_cnt[APB];
    __shared__ double s_red[16];

    const int tid  = threadIdx.x;
    const int wave = tid >> 6;    // 0..7
    const int lane = tid & 63;
    const int rr   = lane >> 4;   // row-within-quad: 0..3
    const int dd   = lane & 15;   // dim-segment lane: 0..15
    const int a0   = blockIdx.x * APB;

    const float4* x4 = reinterpret_cast<const float4*>(x);

    if (tid < BB) s_lab[tid] = labels[tid];

    // Anchor fragments in registers: xa[j][k] = float4 f = 16k + dd of row a0+j.
    float4 xa[APB][4];
#pragma unroll
    for (int j = 0; j < APB; ++j)
#pragma unroll
        for (int k = 0; k < 4; ++k)
            xa[j][k] = x4[(a0 + j) * F4 + k * 16 + dd];

    // ---- dist rows: each wave covers 48 rows, 4 rows/iter, 16 loads in flight
    const int rbeg = wave * 48;
#pragma unroll 4
    for (int b0 = rbeg; b0 < rbeg + 48; b0 += 4) {
        const int b = b0 + rr;
        float4 row[4];
#pragma unroll
        for (int k = 0; k < 4; ++k)
            row[k] = x4[b * F4 + k * 16 + dd];

        float s[APB];
#pragma unroll
        for (int j = 0; j < APB; ++j) {
            float sx = 0.f, sy = 0.f, sz = 0.f, sw = 0.f;
#pragma unroll
            for (int k = 0; k < 4; ++k) {
                float dx = row[k].x - xa[j][k].x;
                float dy = row[k].y - xa[j][k].y;
                float dz = row[k].z - xa[j][k].z;
                float dw = row[k].w - xa[j][k].w;
                sx += dx * dx;
                sy += dy * dy;
                sz += dz * dz;
                sw += dw * dw;
            }
            s[j] = (sx + sy) + (sz + sw);
        }
        // 16-lane butterfly (stays within the rr segment for masks 1,2,4,8)
#pragma unroll
        for (int mask = 1; mask < 16; mask <<= 1)
#pragma unroll
            for (int j = 0; j < APB; ++j)
                s[j] += __shfl_xor(s[j], mask, 64);

        if (dd == 0) s_d[0][b] = s[0];
        if (dd == 1) s_d[1][b] = s[1];
    }

    // ---- triplet phase: block halves handle the two anchors concurrently ----
    const int half = tid >> 8;    // 0 or 1 -> anchor index within block
    const int t2   = tid & 255;   // thread index within half
    const int a    = a0 + half;

    if (t2 == 0) { s_np[half] = 0; s_cnt[half] = 0; }
    __syncthreads();  // covers s_d writes, s_lab loads, and the inits

    const int la = s_lab[a];
    const float* dj = s_d[half];
    for (int i = t2; i < BB; i += 256) {
        if (s_lab[i] == la) {
            atomicAdd(&s_cnt[half], 1);
            if (i > a) {
                int k = atomicAdd(&s_np[half], 1);
                s_t[half][k] = MARGIN + dj[i];
            }
        }
    }
    __syncthreads();

    const int np  = s_np[half];
    const int cnt = s_cnt[half];

    double num_local = 0.0;
    for (int n = t2; n < BB; n += 256) {
        if (s_lab[n] != la) {
            const float dn = dj[n];
            for (int pi = 0; pi < np; ++pi) {
                float l = s_t[half][pi] - dn;
                if (l > 0.f) num_local += (double)l;
            }
        }
    }

    for (int off = 32; off > 0; off >>= 1)
        num_local += __shfl_down(num_local, off, 64);
    if (lane == 0) s_red[wave] = num_local;
    __syncthreads();

    if (tid == 0) {
        double tot = (s_red[0] + s_red[1]) + (s_red[2] + s_red[3]);
        partial_num[a] = tot * (double)cnt;
        partial_den[a] = (double)cnt * (double)np * (double)(BB - cnt);
    } else if (tid == 256) {
        double tot = (s_red[4] + s_red[5]) + (s_red[6] + s_red[7]);
        partial_num[a] = tot * (double)cnt;
        partial_den[a] = (double)cnt * (double)np * (double)(BB - cnt);
    }

    // ---- grid-wide sync, then block 0 finalizes (replaces 2nd kernel) ----
    cg::this_grid().sync();

    if (blockIdx.x == 0) {
        double n_local = 0.0, d_local = 0.0;
        for (int i = tid; i < BB; i += NT) {
            n_local += partial_num[i];
            d_local += partial_den[i];
        }
        for (int off = 32; off > 0; off >>= 1) {
            n_local += __shfl_down(n_local, off, 64);
            d_local += __shfl_down(d_local, off, 64);
        }
        if (lane == 0) { s_red[wave] = n_local; s_red[8 + wave] = d_local; }
        __syncthreads();

        if (tid == 0) {
            double num = ((s_red[0] + s_red[1]) + (s_red[2] + s_red[3])) +
                         ((s_red[4] + s_red[5]) + (s_red[6] + s_red[7]));
            double den = ((s_red[8] + s_red[9]) + (s_red[10] + s_red[11])) +
                         ((s_red[12] + s_red[13]) + (s_red[14] + s_red[15]));
            out[0] = (den > 0.0) ? (float)(num / den) : 0.0f;
        }
    }
}

extern "C" void kernel_launch(void* const* d_in, const int* in_sizes, int n_in,
                              void* d_out, int out_size, void* d_ws, size_t ws_size,
                              hipStream_t stream) {
    const float* x = (const float*)d_in[0];
    const int* labels = (const int*)d_in[1];
    float* out = (float*)d_out;

    double* partial_num = (double*)d_ws;
    double* partial_den = partial_num + BB;

    void* args[] = {(void*)&x, (void*)&labels, (void*)&partial_num,
                    (void*)&partial_den, (void*)&out};
    hipLaunchCooperativeKernel(reinterpret_cast<void*>(triplet_coop_kernel),
                               dim3(NBLK), dim3(NT), args, 0, stream);
}

// Round 3
// 74.979 us; speedup vs baseline: 1.3422x; 1.3422x over previous
//
#include <hip/hip_runtime.h>

#define BB 384
#define DD 256           // floats per row; 64 float4
#define F4 (DD / 4)      // 64
#define APB 2            // anchors per block
#define NBLK (BB / APB)  // 192 blocks
#define NT 512           // 8 waves/block -> 1536 waves on 1024 SIMDs
#define MARGIN 0.2f

// Workspace layout (zeroed by the 24B memset each iteration):
//   ws[0] = g_num (double), ws[1] = g_den (double), ws[2] = g_ticket (as u64)

// ---------------------------------------------------------------------------
// Single regular-launch kernel: one block (512 threads) per APB=2 anchors.
// Dist phase: 8 waves x 48 rows, 4 rows/iter, unroll 4 => 16 float4 loads in
// flight per wave (hides cold-HBM latency after the 256MiB poison fill).
// lane = 16*rr + dd; one instruction reads float4 f=16k+dd of rows b0+rr
// (4 contiguous 256B segments). Anchor fragments in registers; 16-lane
// shfl_xor butterfly reduces each row's diff^2 partials.
// Triplet phase: block halves process the two anchors CONCURRENTLY.
// Tail: per-block atomicAdd(double) of num/den (device-scope, cross-XCD
// coherent), threadfence, ticket; last block atomically reads totals and
// writes out — replaces the 1-block finalize dispatch. NO cooperative
// launch (round 2 showed coop costs ~35us/replay in graph capture).
// ---------------------------------------------------------------------------
__global__ __launch_bounds__(NT) void triplet_fused_kernel(
    const float* __restrict__ x,
    const int* __restrict__ labels,
    double* __restrict__ g_num,
    double* __restrict__ g_den,
    unsigned long long* __restrict__ g_ticket,
    float* __restrict__ out) {
    __shared__ int    s_lab[BB];
    __shared__ float  s_d[APB][BB];
    __shared__ float  s_t[APB][BB];   // margin + d[a, p] for each positive
    __shared__ int    s_np[APB], s_cnt[APB];
    __shared__ double s_red[8];

    const int tid  = threadIdx.x;
    const int wave = tid >> 6;    // 0..7
    const int lane = tid & 63;
    const int rr   = lane >> 4;   // row-within-quad: 0..3
    const int dd   = lane & 15;   // dim-segment lane: 0..15
    const int a0   = blockIdx.x * APB;

    const float4* x4 = reinterpret_cast<const float4*>(x);

    if (tid < BB) s_lab[tid] = labels[tid];

    // Anchor fragments in registers: xa[j][k] = float4 f = 16k + dd of row a0+j.
    float4 xa[APB][4];
#pragma unroll
    for (int j = 0; j < APB; ++j)
#pragma unroll
        for (int k = 0; k < 4; ++k)
            xa[j][k] = x4[(a0 + j) * F4 + k * 16 + dd];

    // ---- dist rows: each wave covers 48 rows, 4 rows/iter, 16 loads in flight
    const int rbeg = wave * 48;
#pragma unroll 4
    for (int b0 = rbeg; b0 < rbeg + 48; b0 += 4) {
        const int b = b0 + rr;
        float4 row[4];
#pragma unroll
        for (int k = 0; k < 4; ++k)
            row[k] = x4[b * F4 + k * 16 + dd];

        float s[APB];
#pragma unroll
        for (int j = 0; j < APB; ++j) {
            float sx = 0.f, sy = 0.f, sz = 0.f, sw = 0.f;
#pragma unroll
            for (int k = 0; k < 4; ++k) {
                float dx = row[k].x - xa[j][k].x;
                float dy = row[k].y - xa[j][k].y;
                float dz = row[k].z - xa[j][k].z;
                float dw = row[k].w - xa[j][k].w;
                sx += dx * dx;
                sy += dy * dy;
                sz += dz * dz;
                sw += dw * dw;
            }
            s[j] = (sx + sy) + (sz + sw);
        }
        // 16-lane butterfly (stays within the rr segment for masks 1,2,4,8)
#pragma unroll
        for (int mask = 1; mask < 16; mask <<= 1)
#pragma unroll
            for (int j = 0; j < APB; ++j)
                s[j] += __shfl_xor(s[j], mask, 64);

        if (dd == 0) s_d[0][b] = s[0];
        if (dd == 1) s_d[1][b] = s[1];
    }

    // ---- triplet phase: block halves handle the two anchors concurrently ----
    const int half = tid >> 8;    // 0 or 1 -> anchor index within block
    const int t2   = tid & 255;   // thread index within half
    const int a    = a0 + half;

    if (t2 == 0) { s_np[half] = 0; s_cnt[half] = 0; }
    __syncthreads();  // covers s_d writes, s_lab loads, and the inits

    const int la = s_lab[a];
    const float* dj = s_d[half];
    for (int i = t2; i < BB; i += 256) {
        if (s_lab[i] == la) {
            atomicAdd(&s_cnt[half], 1);
            if (i > a) {
                int k = atomicAdd(&s_np[half], 1);
                s_t[half][k] = MARGIN + dj[i];
            }
        }
    }
    __syncthreads();

    const int np  = s_np[half];
    const int cnt = s_cnt[half];

    double num_local = 0.0;
    for (int n = t2; n < BB; n += 256) {
        if (s_lab[n] != la) {
            const float dn = dj[n];
            for (int pi = 0; pi < np; ++pi) {
                float l = s_t[half][pi] - dn;
                if (l > 0.f) num_local += (double)l;
            }
        }
    }

    for (int off = 32; off > 0; off >>= 1)
        num_local += __shfl_down(num_local, off, 64);
    if (lane == 0) s_red[wave] = num_local;
    __syncthreads();

    // ---- block tail: accumulate into device-scope doubles, ticket, finish
    if (tid == 0) {
        const int np0 = s_np[0], cnt0 = s_cnt[0];
        const int np1 = s_np[1], cnt1 = s_cnt[1];
        double tot0 = (s_red[0] + s_red[1]) + (s_red[2] + s_red[3]);
        double tot1 = (s_red[4] + s_red[5]) + (s_red[6] + s_red[7]);
        double bnum = tot0 * (double)cnt0 + tot1 * (double)cnt1;
        double bden = (double)cnt0 * (double)np0 * (double)(BB - cnt0) +
                      (double)cnt1 * (double)np1 * (double)(BB - cnt1);
        atomicAdd(g_num, bnum);
        atomicAdd(g_den, bden);
        __threadfence();  // order accumulators before the ticket
        unsigned long long old = atomicAdd(g_ticket, 1ULL);
        if (old == (unsigned long long)(NBLK - 1)) {
            // last block: coherent atomic reads of the totals
            __threadfence();
            double num = atomicAdd(g_num, 0.0);
            double den = atomicAdd(g_den, 0.0);
            out[0] = (den > 0.0) ? (float)(num / den) : 0.0f;
        }
    }
}

extern "C" void kernel_launch(void* const* d_in, const int* in_sizes, int n_in,
                              void* d_out, int out_size, void* d_ws, size_t ws_size,
                              hipStream_t stream) {
    const float* x = (const float*)d_in[0];
    const int* labels = (const int*)d_in[1];
    float* out = (float*)d_out;

    double* g_num = (double*)d_ws;
    double* g_den = g_num + 1;
    unsigned long long* g_ticket = (unsigned long long*)(g_den + 1);

    // zero the 24 bytes of accumulators/ticket (workspace is poisoned each run)
    hipMemsetAsync(d_ws, 0, 3 * sizeof(double), stream);

    triplet_fused_kernel<<<NBLK, NT, 0, stream>>>(x, labels, g_num, g_den,
                                                  g_ticket, out);
}

// Round 4
// 66.235 us; speedup vs baseline: 1.5194x; 1.1320x over previous
//
#include <hip/hip_runtime.h>

#define BB 384
#define DD 256           // floats per row; 64 float4
#define F4 (DD / 4)      // 64
#define APB 2            // anchors per block
#define NBLK (BB / APB)  // 192 blocks
#define NT 512           // 8 waves/block -> 1536 waves on 1024 SIMDs
#define MARGIN 0.2f

// ---------------------------------------------------------------------------
// Verified round-1 structure (65.5us): two regular launches. Coop launch
// (+35us) and single-kernel atomic tail w/ threadfence (+9.5us vs this)
// both regressed — threadfence's L2 writeback is expensive right after the
// 256MiB poison fill dirties all XCD L2s.
//
// Fused kernel: one block (512 threads) per APB=2 anchors.
// Dist phase: 8 waves x 48 rows, 4 rows/iter, unroll 2 => 8 float4 loads in
// flight per wave. lane = 16*rr + dd; one instruction reads float4 f=16k+dd
// of rows b0+rr (4 contiguous 256B segments). Anchor fragments in registers;
// 16-lane shfl_xor butterfly reduces each row's diff^2 partials.
// Triplet phase: block halves process the two anchors CONCURRENTLY
// (tid<256 -> anchor a0, tid>=256 -> anchor a0+1), thresholds precomputed.
// Tail: tid 0 writes ONE combined num/den pair per block (192 pairs, not
// 384) — halves finalize's reads at zero structural risk.
// ---------------------------------------------------------------------------
__global__ __launch_bounds__(NT) void triplet_fused_kernel(
    const float* __restrict__ x,
    const int* __restrict__ labels,
    double* __restrict__ partial_num,
    double* __restrict__ partial_den) {
    __shared__ int    s_lab[BB];
    __shared__ float  s_d[APB][BB];
    __shared__ float  s_t[APB][BB];   // margin + d[a, p] for each positive
    __shared__ int    s_np[APB], s_cnt[APB];
    __shared__ double s_red[8];

    const int tid  = threadIdx.x;
    const int wave = tid >> 6;    // 0..7
    const int lane = tid & 63;
    const int rr   = lane >> 4;   // row-within-quad: 0..3
    const int dd   = lane & 15;   // dim-segment lane: 0..15
    const int a0   = blockIdx.x * APB;

    const float4* x4 = reinterpret_cast<const float4*>(x);

    if (tid < BB) s_lab[tid] = labels[tid];

    // Anchor fragments in registers: xa[j][k] = float4 f = 16k + dd of row a0+j.
    float4 xa[APB][4];
#pragma unroll
    for (int j = 0; j < APB; ++j)
#pragma unroll
        for (int k = 0; k < 4; ++k)
            xa[j][k] = x4[(a0 + j) * F4 + k * 16 + dd];

    // ---- dist rows: each wave covers 48 rows, 4 rows per iteration ----
    const int rbeg = wave * 48;
#pragma unroll 2
    for (int b0 = rbeg; b0 < rbeg + 48; b0 += 4) {
        const int b = b0 + rr;
        float4 row[4];
#pragma unroll
        for (int k = 0; k < 4; ++k)
            row[k] = x4[b * F4 + k * 16 + dd];

        float s[APB];
#pragma unroll
        for (int j = 0; j < APB; ++j) {
            float sx = 0.f, sy = 0.f, sz = 0.f, sw = 0.f;
#pragma unroll
            for (int k = 0; k < 4; ++k) {
                float dx = row[k].x - xa[j][k].x;
                float dy = row[k].y - xa[j][k].y;
                float dz = row[k].z - xa[j][k].z;
                float dw = row[k].w - xa[j][k].w;
                sx += dx * dx;
                sy += dy * dy;
                sz += dz * dz;
                sw += dw * dw;
            }
            s[j] = (sx + sy) + (sz + sw);
        }
        // 16-lane butterfly (stays within the rr segment for masks 1,2,4,8)
#pragma unroll
        for (int mask = 1; mask < 16; mask <<= 1)
#pragma unroll
            for (int j = 0; j < APB; ++j)
                s[j] += __shfl_xor(s[j], mask, 64);

        if (dd == 0) s_d[0][b] = s[0];
        if (dd == 1) s_d[1][b] = s[1];
    }

    // ---- triplet phase: block halves handle the two anchors concurrently ----
    const int half = tid >> 8;    // 0 or 1 -> anchor index within block
    const int t2   = tid & 255;   // thread index within half
    const int a    = a0 + half;

    if (t2 == 0) { s_np[half] = 0; s_cnt[half] = 0; }
    __syncthreads();  // covers s_d writes, s_lab loads, and the inits

    const int la = s_lab[a];
    const float* dj = s_d[half];
    for (int i = t2; i < BB; i += 256) {
        if (s_lab[i] == la) {
            atomicAdd(&s_cnt[half], 1);
            if (i > a) {
                int k = atomicAdd(&s_np[half], 1);
                s_t[half][k] = MARGIN + dj[i];
            }
        }
    }
    __syncthreads();

    const int np  = s_np[half];
    const int cnt = s_cnt[half];

    double num_local = 0.0;
    for (int n = t2; n < BB; n += 256) {
        if (s_lab[n] != la) {
            const float dn = dj[n];
            for (int pi = 0; pi < np; ++pi) {
                float l = s_t[half][pi] - dn;
                if (l > 0.f) num_local += (double)l;
            }
        }
    }

    for (int off = 32; off > 0; off >>= 1)
        num_local += __shfl_down(num_local, off, 64);
    if (lane == 0) s_red[wave] = num_local;
    __syncthreads();

    if (tid == 0) {
        const int np0 = s_np[0], cnt0 = s_cnt[0];
        const int np1 = s_np[1], cnt1 = s_cnt[1];
        double tot0 = (s_red[0] + s_red[1]) + (s_red[2] + s_red[3]);
        double tot1 = (s_red[4] + s_red[5]) + (s_red[6] + s_red[7]);
        partial_num[blockIdx.x] = tot0 * (double)cnt0 + tot1 * (double)cnt1;
        partial_den[blockIdx.x] =
            (double)cnt0 * (double)np0 * (double)(BB - cnt0) +
            (double)cnt1 * (double)np1 * (double)(BB - cnt1);
    }
}

// ---------------------------------------------------------------------------
// Finalize: reduce 192 partial num/den pairs, emit num/den.
// ---------------------------------------------------------------------------
__global__ __launch_bounds__(256) void finalize_kernel(
    const double* __restrict__ partial_num,
    const double* __restrict__ partial_den,
    float* __restrict__ out) {
    __shared__ double s_red[8];
    const int tid = threadIdx.x;

    double n_local = 0.0, d_local = 0.0;
    if (tid < NBLK) {
        n_local = partial_num[tid];
        d_local = partial_den[tid];
    }
    for (int off = 32; off > 0; off >>= 1) {
        n_local += __shfl_down(n_local, off, 64);
        d_local += __shfl_down(d_local, off, 64);
    }
    const int lane = tid & 63, wid = tid >> 6;
    if (lane == 0) { s_red[wid] = n_local; s_red[4 + wid] = d_local; }
    __syncthreads();

    if (tid == 0) {
        double num = (s_red[0] + s_red[1]) + (s_red[2] + s_red[3]);
        double den = (s_red[4] + s_red[5]) + (s_red[6] + s_red[7]);
        out[0] = (den > 0.0) ? (float)(num / den) : 0.0f;
    }
}

extern "C" void kernel_launch(void* const* d_in, const int* in_sizes, int n_in,
                              void* d_out, int out_size, void* d_ws, size_t ws_size,
                              hipStream_t stream) {
    const float* x = (const float*)d_in[0];
    const int* labels = (const int*)d_in[1];
    float* out = (float*)d_out;

    double* partial_num = (double*)d_ws;
    double* partial_den = partial_num + NBLK;

    triplet_fused_kernel<<<NBLK, NT, 0, stream>>>(x, labels, partial_num, partial_den);
    finalize_kernel<<<1, 256, 0, stream>>>(partial_num, partial_den, out);
}